// Round 12
// baseline (393.320 us; speedup 1.0000x reference)
//
#include <hip/hip_runtime.h>
#include <stdint.h>

#define N_ROWS 12288
#define GSZ (128 * 12288)  // elements per gt matrix (bf16)
#define NPART_OFF (9437184 / 4)          // float offset of node partials in ws
#define EPART_OFF ((9437184 + 6291456) / 4)

typedef __attribute__((ext_vector_type(8))) short bf16x8;
typedef __attribute__((ext_vector_type(4))) float f32x4;

union frag_u { bf16x8 v; uint32_t u[4]; };

__device__ __forceinline__ uint32_t f2bf(float x) {
  union { float f; uint32_t u; } c; c.f = x;
  return (c.u + 0x7FFFu + ((c.u >> 16) & 1u)) >> 16;
}
__device__ __forceinline__ uint32_t pk_bf(float a, float b) {
  return f2bf(a) | (f2bf(b) << 16);
}
__device__ __forceinline__ uint32_t sgn_h(float a) {
  return a > 0.f ? 0x3F80u : (a < 0.f ? 0xBF80u : 0u);
}
__device__ __forceinline__ uint32_t pk_sgn(float a, float b) {
  return sgn_h(a) | (sgn_h(b) << 16);
}

#define MFMA __builtin_amdgcn_mfma_f32_16x16x32_bf16

// ---------------------------------------------------------------------------
// Kernel 1 (R9-verified): build three bf16 TRANSPOSED matrices in gt:
//   mat0 = Gm = (feats@Wtop - feats@Wbot)/2   (pairs with S = sgn(node_adj))
//   mat1 = Gp = (feats@Wtop + feats@Wbot)/2   (pairs with A = |S|)
//   mat2 = Ge = feats@edge_w
// gt[m][n][k] = G[k][n];  pos@G1+neg@G2 == S@Gm + A@Gp.
// ---------------------------------------------------------------------------
__global__ __launch_bounds__(256) void gw_kernel(
    const float* __restrict__ feats, const float* __restrict__ node_w,
    const float* __restrict__ edge_w, uint16_t* __restrict__ gt) {
  __shared__ float lf[16 * 128];
  const int t = threadIdx.x;
  const int kb = blockIdx.x * 16;
  {
    const float4* src = (const float4*)(feats + (size_t)kb * 128);
    float4* dst = (float4*)lf;
    dst[t] = src[t];
    dst[t + 256] = src[t + 256];
  }
  __syncthreads();
  const int n = t & 127;
  const int rh = t >> 7;

  float accT[8], accB[8];
#pragma unroll
  for (int q = 0; q < 8; ++q) { accT[q] = 0.f; accB[q] = 0.f; }
  {
    const float* WT = node_w + n;
    const float* WB = node_w + 128 * 128 + n;
    for (int i = 0; i < 128; i += 2) {
      const float t0 = WT[(i + 0) * 128], t1 = WT[(i + 1) * 128];
      const float b0 = WB[(i + 0) * 128], b1 = WB[(i + 1) * 128];
#pragma unroll
      for (int q = 0; q < 8; ++q) {
        const float f0 = lf[(rh * 8 + q) * 128 + i];
        const float f1 = lf[(rh * 8 + q) * 128 + i + 1];
        accT[q] = fmaf(f1, t1, fmaf(f0, t0, accT[q]));
        accB[q] = fmaf(f1, b1, fmaf(f0, b0, accB[q]));
      }
    }
  }
  {
    uint4 o;  // Gm
    o.x = pk_bf((accT[0] - accB[0]) * 0.5f, (accT[1] - accB[1]) * 0.5f);
    o.y = pk_bf((accT[2] - accB[2]) * 0.5f, (accT[3] - accB[3]) * 0.5f);
    o.z = pk_bf((accT[4] - accB[4]) * 0.5f, (accT[5] - accB[5]) * 0.5f);
    o.w = pk_bf((accT[6] - accB[6]) * 0.5f, (accT[7] - accB[7]) * 0.5f);
    *(uint4*)(gt + (size_t)n * N_ROWS + kb + rh * 8) = o;
    uint4 p;  // Gp
    p.x = pk_bf((accT[0] + accB[0]) * 0.5f, (accT[1] + accB[1]) * 0.5f);
    p.y = pk_bf((accT[2] + accB[2]) * 0.5f, (accT[3] + accB[3]) * 0.5f);
    p.z = pk_bf((accT[4] + accB[4]) * 0.5f, (accT[5] + accB[5]) * 0.5f);
    p.w = pk_bf((accT[6] + accB[6]) * 0.5f, (accT[7] + accB[7]) * 0.5f);
    *(uint4*)(gt + GSZ + (size_t)n * N_ROWS + kb + rh * 8) = p;
  }
  {
    float accE[8];
#pragma unroll
    for (int q = 0; q < 8; ++q) accE[q] = 0.f;
    const float* WE = edge_w + n;
    for (int i = 0; i < 128; i += 2) {
      const float e0 = WE[(i + 0) * 128], e1 = WE[(i + 1) * 128];
#pragma unroll
      for (int q = 0; q < 8; ++q) {
        const float f0 = lf[(rh * 8 + q) * 128 + i];
        const float f1 = lf[(rh * 8 + q) * 128 + i + 1];
        accE[q] = fmaf(f1, e1, fmaf(f0, e0, accE[q]));
      }
    }
    uint4 o;
    o.x = pk_bf(accE[0], accE[1]);
    o.y = pk_bf(accE[2], accE[3]);
    o.z = pk_bf(accE[4], accE[5]);
    o.w = pk_bf(accE[6], accE[7]);
    *(uint4*)(gt + 2 * (size_t)GSZ + (size_t)n * N_ROWS + kb + rh * 8) = o;
  }
}

// ---------------------------------------------------------------------------
// Kernel 2: BM=192 + S/A fold. 1024 blocks x 512 thr (8 waves), exactly
// 2 blocks/CU (LDS 24KB x 2, VGPR <=128 via __launch_bounds__(512,4)) ->
// two clean uniformly-balanced residency rounds (512 node, 512 edge).
// bid<512: NODE -- stage S=sgn(adj) (ONE plane), A=|S| derived in-register,
//   acc += S@Gm + A@Gp (2 B-loads). bid>=512: EDGE -- stage bf16(adj),
//   acc += E@Ge (1 B-load). BK=32, 8 K-slices of 1536 (48 iters),
// slice=(b>>6)&7 pins an XCD's blocks to <=2 slices (gt bands L2-fit).
// Bytes: adj 1.21GB + B 0.59GB + atomics ~0.1GB = 1.88GB vs R11's 2.2GB
// (measured wall: ~7.3 TB/s combined vector-load bytes, all levels).
// LDS: 2 bufs x 192 rows x 32 bf16 (64B rows); granule swizzle g^((r>>1)&3).
// Per-iter structure = proven R11: pack+ds_write, __syncthreads, prefetch,
// B-loads + MFMA. Wave w owns cols [w*16,w*16+16): mf=12, nf=1.
// ---------------------------------------------------------------------------
__global__ __launch_bounds__(512, 4) void fgc_main(
    const float* __restrict__ node_adj, const float* __restrict__ edge_adj,
    const uint16_t* __restrict__ gt, float* __restrict__ node_part,
    float* __restrict__ edge_part) {
  __shared__ __align__(128) char smem[24576];
  const int t = threadIdx.x;
  const int l = t & 63;
  const int w = t >> 6;  // 0..7: n-slice
  const bool isNode = (blockIdx.x < 512);
  const int b = isNode ? blockIdx.x : (blockIdx.x - 512);
  const int tile = b & 63;           // 64 row-tiles of 192
  const int slice = (b >> 6) & 7;    // 8 K-slices
  const int row0 = tile * 192;
  const size_t k0 = (size_t)slice * 1536;

  // staging: threads 0-383; thread -> (row t>>1, half t&1) = 16 consec f32
  const bool stg = (t < 384);
  const int r = t >> 1, h = t & 1;
  const float* src = (isNode ? node_adj : edge_adj) +
                     (size_t)(row0 + r) * N_ROWS + k0 + h * 16;
  const int sw = (r >> 1) & 3;
  const int wOffA = r * 64 + (((h * 2) ^ sw) * 16);
  const int wOffB = r * 64 + (((h * 2 + 1) ^ sw) * 16);

  // consumer fragment addressing
  const int r15 = l & 15;
  const int gq = l >> 4;

  // B lane base: n = w*16 + r15, k = k0 + kt*32 + gq*8
  const uint16_t* gB = gt + (size_t)(w * 16 + r15) * N_ROWS + k0 + gq * 8;

  f32x4 acc[12];
#pragma unroll
  for (int a = 0; a < 12; ++a) acc[a] = {0.f, 0.f, 0.f, 0.f};

  float4 x0, x1, x2, x3;
  if (stg) {
    x0 = *(const float4*)(src);
    x1 = *(const float4*)(src + 4);
    x2 = *(const float4*)(src + 8);
    x3 = *(const float4*)(src + 12);
  }

  if (isNode) {
    for (int kt = 0; kt < 48; ++kt) {
      char* wb2 = smem + (kt & 1) * 12288;
      if (stg) {
        uint4 P;
        P.x = pk_sgn(x0.x, x0.y); P.y = pk_sgn(x0.z, x0.w);
        P.z = pk_sgn(x1.x, x1.y); P.w = pk_sgn(x1.z, x1.w);
        *(uint4*)(wb2 + wOffA) = P;
        P.x = pk_sgn(x2.x, x2.y); P.y = pk_sgn(x2.z, x2.w);
        P.z = pk_sgn(x3.x, x3.y); P.w = pk_sgn(x3.z, x3.w);
        *(uint4*)(wb2 + wOffB) = P;
      }
      __syncthreads();
      if (stg && kt < 47) {
        const float* s2 = src + (size_t)(kt + 1) * 32;
        x0 = *(const float4*)(s2);
        x1 = *(const float4*)(s2 + 4);
        x2 = *(const float4*)(s2 + 8);
        x3 = *(const float4*)(s2 + 12);
      }
      const char* rb = smem + (kt & 1) * 12288;
      const uint16_t* gk = gB + kt * 32;
      const bf16x8 bm = *(const bf16x8*)(gk);
      const bf16x8 bp = *(const bf16x8*)(gk + GSZ);
#pragma unroll
      for (int mf = 0; mf < 12; ++mf) {
        const int rowR = mf * 16 + r15;
        const int aoff = rowR * 64 + ((gq ^ ((rowR >> 1) & 3)) * 16);
        frag_u s, a;
        s.v = *(const bf16x8*)(rb + aoff);
        a.u[0] = s.u[0] & 0x7FFF7FFFu;
        a.u[1] = s.u[1] & 0x7FFF7FFFu;
        a.u[2] = s.u[2] & 0x7FFF7FFFu;
        a.u[3] = s.u[3] & 0x7FFF7FFFu;
        acc[mf] = MFMA(s.v, bm, acc[mf], 0, 0, 0);
        acc[mf] = MFMA(a.v, bp, acc[mf], 0, 0, 0);
      }
    }
    const int col = w * 16 + r15;
#pragma unroll
    for (int mf = 0; mf < 12; ++mf) {
      const f32x4 nv = acc[mf];
#pragma unroll
      for (int q = 0; q < 4; ++q) {
        const size_t idx = (size_t)(row0 + mf * 16 + gq * 4 + q) * 128 + col;
        unsafeAtomicAdd(&node_part[idx], nv[q]);
      }
    }
  } else {
    for (int kt = 0; kt < 48; ++kt) {
      char* wb2 = smem + (kt & 1) * 12288;
      if (stg) {
        uint4 E;
        E.x = pk_bf(x0.x, x0.y); E.y = pk_bf(x0.z, x0.w);
        E.z = pk_bf(x1.x, x1.y); E.w = pk_bf(x1.z, x1.w);
        *(uint4*)(wb2 + wOffA) = E;
        E.x = pk_bf(x2.x, x2.y); E.y = pk_bf(x2.z, x2.w);
        E.z = pk_bf(x3.x, x3.y); E.w = pk_bf(x3.z, x3.w);
        *(uint4*)(wb2 + wOffB) = E;
      }
      __syncthreads();
      if (stg && kt < 47) {
        const float* s2 = src + (size_t)(kt + 1) * 32;
        x0 = *(const float4*)(s2);
        x1 = *(const float4*)(s2 + 4);
        x2 = *(const float4*)(s2 + 8);
        x3 = *(const float4*)(s2 + 12);
      }
      const char* rb = smem + (kt & 1) * 12288;
      const bf16x8 be = *(const bf16x8*)(gB + kt * 32 + 2 * (size_t)GSZ);
#pragma unroll
      for (int mf = 0; mf < 12; ++mf) {
        const int rowR = mf * 16 + r15;
        const int aoff = rowR * 64 + ((gq ^ ((rowR >> 1) & 3)) * 16);
        const bf16x8 ae = *(const bf16x8*)(rb + aoff);
        acc[mf] = MFMA(ae, be, acc[mf], 0, 0, 0);
      }
    }
    const int col = w * 16 + r15;
#pragma unroll
    for (int mf = 0; mf < 12; ++mf) {
      const f32x4 ev = acc[mf];
#pragma unroll
      for (int q = 0; q < 4; ++q) {
        const size_t idx = (size_t)(row0 + mf * 16 + gq * 4 + q) * 128 + col;
        unsafeAtomicAdd(&edge_part[idx], ev[q]);
      }
    }
  }
}

// ---------------------------------------------------------------------------
// Kernel 3: out = relu(node_part + node_bias) + edge_part + edge_bias
// ---------------------------------------------------------------------------
__global__ __launch_bounds__(256) void fgc_final(
    const float* __restrict__ node_part, const float* __restrict__ edge_part,
    const float* __restrict__ node_bias, const float* __restrict__ edge_bias,
    float* __restrict__ out) {
  const int idx = blockIdx.x * 256 + threadIdx.x;  // one float4 each
  const int col = (idx * 4) & 127;
  const float4 n = ((const float4*)node_part)[idx];
  const float4 e = ((const float4*)edge_part)[idx];
  const float4 nb = *(const float4*)(node_bias + col);
  const float4 eb = *(const float4*)(edge_bias + col);
  float4 o;
  o.x = fmaxf(n.x + nb.x, 0.f) + e.x + eb.x;
  o.y = fmaxf(n.y + nb.y, 0.f) + e.y + eb.y;
  o.z = fmaxf(n.z + nb.z, 0.f) + e.z + eb.z;
  o.w = fmaxf(n.w + nb.w, 0.f) + e.w + eb.w;
  ((float4*)out)[idx] = o;
}

extern "C" void kernel_launch(void* const* d_in, const int* in_sizes, int n_in,
                              void* d_out, int out_size, void* d_ws, size_t ws_size,
                              hipStream_t stream) {
  const float* feats = (const float*)d_in[0];
  const float* node_adj = (const float*)d_in[1];
  const float* edge_adj = (const float*)d_in[2];
  const float* node_w = (const float*)d_in[3];
  const float* node_b = (const float*)d_in[4];
  const float* edge_w = (const float*)d_in[5];
  const float* edge_b = (const float*)d_in[6];
  uint16_t* gt = (uint16_t*)d_ws;                 // 9.44 MB
  float* node_part = (float*)d_ws + NPART_OFF;    // 6.29 MB
  float* edge_part = (float*)d_ws + EPART_OFF;    // 6.29 MB

  gw_kernel<<<768, 256, 0, stream>>>(feats, node_w, edge_w, gt);
  hipMemsetAsync((char*)d_ws + 9437184, 0, 2 * 6291456, stream);
  fgc_main<<<1024, 512, 0, stream>>>(node_adj, edge_adj, gt,
                                     node_part, edge_part);
  fgc_final<<<1536, 256, 0, stream>>>(node_part, edge_part, node_b, edge_b,
                                      (float*)d_out);
}

// Round 13
// 393.311 us; speedup vs baseline: 1.0000x; 1.0000x over previous
//
#include <hip/hip_runtime.h>
#include <stdint.h>

#define N_ROWS 12288
#define GSZ (128 * 12288)  // elements per gt matrix (bf16)
#define NPART_OFF (9437184 / 4)          // float offset of node partials in ws
#define EPART_OFF ((9437184 + 6291456) / 4)

typedef __attribute__((ext_vector_type(8))) short bf16x8;
typedef __attribute__((ext_vector_type(4))) float f32x4;

union frag_u { bf16x8 v; uint32_t u[4]; };

__device__ __forceinline__ uint32_t f2bf(float x) {
  union { float f; uint32_t u; } c; c.f = x;
  return (c.u + 0x7FFFu + ((c.u >> 16) & 1u)) >> 16;
}
__device__ __forceinline__ uint32_t pk_bf(float a, float b) {
  return f2bf(a) | (f2bf(b) << 16);
}
__device__ __forceinline__ uint32_t sgn_h(float a) {
  return a > 0.f ? 0x3F80u : (a < 0.f ? 0xBF80u : 0u);
}
__device__ __forceinline__ uint32_t pk_sgn(float a, float b) {
  return sgn_h(a) | (sgn_h(b) << 16);
}

#define MFMA __builtin_amdgcn_mfma_f32_16x16x32_bf16

// ---------------------------------------------------------------------------
// Kernel 1 (R9-verified): build three bf16 TRANSPOSED matrices in gt:
//   mat0 = Gm = (feats@Wtop - feats@Wbot)/2   (pairs with S = sgn(node_adj))
//   mat1 = Gp = (feats@Wtop + feats@Wbot)/2   (pairs with A = |S|)
//   mat2 = Ge = feats@edge_w
// gt[m][n][k] = G[k][n];  pos@G1+neg@G2 == S@Gm + A@Gp.
// ---------------------------------------------------------------------------
__global__ __launch_bounds__(256) void gw_kernel(
    const float* __restrict__ feats, const float* __restrict__ node_w,
    const float* __restrict__ edge_w, uint16_t* __restrict__ gt) {
  __shared__ float lf[16 * 128];
  const int t = threadIdx.x;
  const int kb = blockIdx.x * 16;
  {
    const float4* src = (const float4*)(feats + (size_t)kb * 128);
    float4* dst = (float4*)lf;
    dst[t] = src[t];
    dst[t + 256] = src[t + 256];
  }
  __syncthreads();
  const int n = t & 127;
  const int rh = t >> 7;

  float accT[8], accB[8];
#pragma unroll
  for (int q = 0; q < 8; ++q) { accT[q] = 0.f; accB[q] = 0.f; }
  {
    const float* WT = node_w + n;
    const float* WB = node_w + 128 * 128 + n;
    for (int i = 0; i < 128; i += 2) {
      const float t0 = WT[(i + 0) * 128], t1 = WT[(i + 1) * 128];
      const float b0 = WB[(i + 0) * 128], b1 = WB[(i + 1) * 128];
#pragma unroll
      for (int q = 0; q < 8; ++q) {
        const float f0 = lf[(rh * 8 + q) * 128 + i];
        const float f1 = lf[(rh * 8 + q) * 128 + i + 1];
        accT[q] = fmaf(f1, t1, fmaf(f0, t0, accT[q]));
        accB[q] = fmaf(f1, b1, fmaf(f0, b0, accB[q]));
      }
    }
  }
  {
    uint4 o;  // Gm
    o.x = pk_bf((accT[0] - accB[0]) * 0.5f, (accT[1] - accB[1]) * 0.5f);
    o.y = pk_bf((accT[2] - accB[2]) * 0.5f, (accT[3] - accB[3]) * 0.5f);
    o.z = pk_bf((accT[4] - accB[4]) * 0.5f, (accT[5] - accB[5]) * 0.5f);
    o.w = pk_bf((accT[6] - accB[6]) * 0.5f, (accT[7] - accB[7]) * 0.5f);
    *(uint4*)(gt + (size_t)n * N_ROWS + kb + rh * 8) = o;
    uint4 p;  // Gp
    p.x = pk_bf((accT[0] + accB[0]) * 0.5f, (accT[1] + accB[1]) * 0.5f);
    p.y = pk_bf((accT[2] + accB[2]) * 0.5f, (accT[3] + accB[3]) * 0.5f);
    p.z = pk_bf((accT[4] + accB[4]) * 0.5f, (accT[5] + accB[5]) * 0.5f);
    p.w = pk_bf((accT[6] + accB[6]) * 0.5f, (accT[7] + accB[7]) * 0.5f);
    *(uint4*)(gt + GSZ + (size_t)n * N_ROWS + kb + rh * 8) = p;
  }
  {
    float accE[8];
#pragma unroll
    for (int q = 0; q < 8; ++q) accE[q] = 0.f;
    const float* WE = edge_w + n;
    for (int i = 0; i < 128; i += 2) {
      const float e0 = WE[(i + 0) * 128], e1 = WE[(i + 1) * 128];
#pragma unroll
      for (int q = 0; q < 8; ++q) {
        const float f0 = lf[(rh * 8 + q) * 128 + i];
        const float f1 = lf[(rh * 8 + q) * 128 + i + 1];
        accE[q] = fmaf(f1, e1, fmaf(f0, e0, accE[q]));
      }
    }
    uint4 o;
    o.x = pk_bf(accE[0], accE[1]);
    o.y = pk_bf(accE[2], accE[3]);
    o.z = pk_bf(accE[4], accE[5]);
    o.w = pk_bf(accE[6], accE[7]);
    *(uint4*)(gt + 2 * (size_t)GSZ + (size_t)n * N_ROWS + kb + rh * 8) = o;
  }
}

// ---------------------------------------------------------------------------
// Kernel 2: BM=192 + S/A fold + XCD-AFFINE slices (the R12 bug fix:
// slice = b&7 == XCD id since blockIdx round-robins XCDs; R12's (b>>6)&7
// spread all 8 slices across every XCD -> 6.3MB/XCD > 4MB L2 -> B fell to
// L3 -> +90us). Per-XCD gt bands: node 768KB, edge 384KB -- L2-resident.
// 1024 blocks x 512 thr (8 waves), 2 blocks/CU (LDS 24KB x 2, VGPR<=128
// via __launch_bounds__(512,4)) -> two clean balanced residency rounds.
// bid<512: NODE -- stage S=sgn(adj) (ONE plane), A=|S| by AND in-register,
//   acc += S@Gm + A@Gp. bid>=512: EDGE -- stage bf16(adj), acc += E@Ge.
// BK=32, 48 iters. Wave w owns cols [w*16,w*16+16): mf=12, nf=1.
// LDS: 2 bufs x 192 rows x 32 bf16 (64B rows); granule swizzle g^((r>>1)&3).
// Per-iter structure = proven R11: pack+ds_write, __syncthreads, prefetch,
// B-loads + MFMA.
// ---------------------------------------------------------------------------
__global__ __launch_bounds__(512, 4) void fgc_main(
    const float* __restrict__ node_adj, const float* __restrict__ edge_adj,
    const uint16_t* __restrict__ gt, float* __restrict__ node_part,
    float* __restrict__ edge_part) {
  __shared__ __align__(128) char smem[24576];
  const int t = threadIdx.x;
  const int l = t & 63;
  const int w = t >> 6;  // 0..7: n-slice
  const bool isNode = (blockIdx.x < 512);
  const int b = isNode ? blockIdx.x : (blockIdx.x - 512);
  const int tile = b >> 3;           // 64 row-tiles of 192
  const int slice = b & 7;           // == XCD id (blockIdx round-robin)
  const int row0 = tile * 192;
  const size_t k0 = (size_t)slice * 1536;

  // staging: threads 0-383; thread -> (row t>>1, half t&1) = 16 consec f32
  const bool stg = (t < 384);
  const int r = t >> 1, h = t & 1;
  const float* src = (isNode ? node_adj : edge_adj) +
                     (size_t)(row0 + r) * N_ROWS + k0 + h * 16;
  const int sw = (r >> 1) & 3;
  const int wOffA = r * 64 + (((h * 2) ^ sw) * 16);
  const int wOffB = r * 64 + (((h * 2 + 1) ^ sw) * 16);

  // consumer fragment addressing
  const int r15 = l & 15;
  const int gq = l >> 4;

  // B lane base: n = w*16 + r15, k = k0 + kt*32 + gq*8
  const uint16_t* gB = gt + (size_t)(w * 16 + r15) * N_ROWS + k0 + gq * 8;

  f32x4 acc[12];
#pragma unroll
  for (int a = 0; a < 12; ++a) acc[a] = {0.f, 0.f, 0.f, 0.f};

  float4 x0, x1, x2, x3;
  if (stg) {
    x0 = *(const float4*)(src);
    x1 = *(const float4*)(src + 4);
    x2 = *(const float4*)(src + 8);
    x3 = *(const float4*)(src + 12);
  }

  if (isNode) {
    for (int kt = 0; kt < 48; ++kt) {
      char* wb2 = smem + (kt & 1) * 12288;
      if (stg) {
        uint4 P;
        P.x = pk_sgn(x0.x, x0.y); P.y = pk_sgn(x0.z, x0.w);
        P.z = pk_sgn(x1.x, x1.y); P.w = pk_sgn(x1.z, x1.w);
        *(uint4*)(wb2 + wOffA) = P;
        P.x = pk_sgn(x2.x, x2.y); P.y = pk_sgn(x2.z, x2.w);
        P.z = pk_sgn(x3.x, x3.y); P.w = pk_sgn(x3.z, x3.w);
        *(uint4*)(wb2 + wOffB) = P;
      }
      __syncthreads();
      if (stg && kt < 47) {
        const float* s2 = src + (size_t)(kt + 1) * 32;
        x0 = *(const float4*)(s2);
        x1 = *(const float4*)(s2 + 4);
        x2 = *(const float4*)(s2 + 8);
        x3 = *(const float4*)(s2 + 12);
      }
      const char* rb = smem + (kt & 1) * 12288;
      const uint16_t* gk = gB + kt * 32;
      const bf16x8 bm = *(const bf16x8*)(gk);
      const bf16x8 bp = *(const bf16x8*)(gk + GSZ);
#pragma unroll
      for (int mf = 0; mf < 12; ++mf) {
        const int rowR = mf * 16 + r15;
        const int aoff = rowR * 64 + ((gq ^ ((rowR >> 1) & 3)) * 16);
        frag_u s, a;
        s.v = *(const bf16x8*)(rb + aoff);
        a.u[0] = s.u[0] & 0x7FFF7FFFu;
        a.u[1] = s.u[1] & 0x7FFF7FFFu;
        a.u[2] = s.u[2] & 0x7FFF7FFFu;
        a.u[3] = s.u[3] & 0x7FFF7FFFu;
        acc[mf] = MFMA(s.v, bm, acc[mf], 0, 0, 0);
        acc[mf] = MFMA(a.v, bp, acc[mf], 0, 0, 0);
      }
    }
    const int col = w * 16 + r15;
#pragma unroll
    for (int mf = 0; mf < 12; ++mf) {
      const f32x4 nv = acc[mf];
#pragma unroll
      for (int q = 0; q < 4; ++q) {
        const size_t idx = (size_t)(row0 + mf * 16 + gq * 4 + q) * 128 + col;
        unsafeAtomicAdd(&node_part[idx], nv[q]);
      }
    }
  } else {
    for (int kt = 0; kt < 48; ++kt) {
      char* wb2 = smem + (kt & 1) * 12288;
      if (stg) {
        uint4 E;
        E.x = pk_bf(x0.x, x0.y); E.y = pk_bf(x0.z, x0.w);
        E.z = pk_bf(x1.x, x1.y); E.w = pk_bf(x1.z, x1.w);
        *(uint4*)(wb2 + wOffA) = E;
        E.x = pk_bf(x2.x, x2.y); E.y = pk_bf(x2.z, x2.w);
        E.z = pk_bf(x3.x, x3.y); E.w = pk_bf(x3.z, x3.w);
        *(uint4*)(wb2 + wOffB) = E;
      }
      __syncthreads();
      if (stg && kt < 47) {
        const float* s2 = src + (size_t)(kt + 1) * 32;
        x0 = *(const float4*)(s2);
        x1 = *(const float4*)(s2 + 4);
        x2 = *(const float4*)(s2 + 8);
        x3 = *(const float4*)(s2 + 12);
      }
      const char* rb = smem + (kt & 1) * 12288;
      const bf16x8 be = *(const bf16x8*)(gB + kt * 32 + 2 * (size_t)GSZ);
#pragma unroll
      for (int mf = 0; mf < 12; ++mf) {
        const int rowR = mf * 16 + r15;
        const int aoff = rowR * 64 + ((gq ^ ((rowR >> 1) & 3)) * 16);
        const bf16x8 ae = *(const bf16x8*)(rb + aoff);
        acc[mf] = MFMA(ae, be, acc[mf], 0, 0, 0);
      }
    }
    const int col = w * 16 + r15;
#pragma unroll
    for (int mf = 0; mf < 12; ++mf) {
      const f32x4 ev = acc[mf];
#pragma unroll
      for (int q = 0; q < 4; ++q) {
        const size_t idx = (size_t)(row0 + mf * 16 + gq * 4 + q) * 128 + col;
        unsafeAtomicAdd(&edge_part[idx], ev[q]);
      }
    }
  }
}

// ---------------------------------------------------------------------------
// Kernel 3: out = relu(node_part + node_bias) + edge_part + edge_bias
// ---------------------------------------------------------------------------
__global__ __launch_bounds__(256) void fgc_final(
    const float* __restrict__ node_part, const float* __restrict__ edge_part,
    const float* __restrict__ node_bias, const float* __restrict__ edge_bias,
    float* __restrict__ out) {
  const int idx = blockIdx.x * 256 + threadIdx.x;  // one float4 each
  const int col = (idx * 4) & 127;
  const float4 n = ((const float4*)node_part)[idx];
  const float4 e = ((const float4*)edge_part)[idx];
  const float4 nb = *(const float4*)(node_bias + col);
  const float4 eb = *(const float4*)(edge_bias + col);
  float4 o;
  o.x = fmaxf(n.x + nb.x, 0.f) + e.x + eb.x;
  o.y = fmaxf(n.y + nb.y, 0.f) + e.y + eb.y;
  o.z = fmaxf(n.z + nb.z, 0.f) + e.z + eb.z;
  o.w = fmaxf(n.w + nb.w, 0.f) + e.w + eb.w;
  ((float4*)out)[idx] = o;
}

extern "C" void kernel_launch(void* const* d_in, const int* in_sizes, int n_in,
                              void* d_out, int out_size, void* d_ws, size_t ws_size,
                              hipStream_t stream) {
  const float* feats = (const float*)d_in[0];
  const float* node_adj = (const float*)d_in[1];
  const float* edge_adj = (const float*)d_in[2];
  const float* node_w = (const float*)d_in[3];
  const float* node_b = (const float*)d_in[4];
  const float* edge_w = (const float*)d_in[5];
  const float* edge_b = (const float*)d_in[6];
  uint16_t* gt = (uint16_t*)d_ws;                 // 9.44 MB
  float* node_part = (float*)d_ws + NPART_OFF;    // 6.29 MB
  float* edge_part = (float*)d_ws + EPART_OFF;    // 6.29 MB

  gw_kernel<<<768, 256, 0, stream>>>(feats, node_w, edge_w, gt);
  hipMemsetAsync((char*)d_ws + 9437184, 0, 2 * 6291456, stream);
  fgc_main<<<1024, 512, 0, stream>>>(node_adj, edge_adj, gt,
                                     node_part, edge_part);
  fgc_final<<<1536, 256, 0, stream>>>(node_part, edge_part, node_b, edge_b,
                                      (float*)d_out);
}